// Round 7
// baseline (513.126 us; speedup 1.0000x reference)
//
#include <hip/hip_runtime.h>
#include <hip/hip_bf16.h>
#include <math.h>

typedef __bf16 bf16;
typedef __bf16 bf16x2_t __attribute__((ext_vector_type(2)));
typedef __bf16 bf16x4_t __attribute__((ext_vector_type(4)));
typedef __bf16 bf16x8_t __attribute__((ext_vector_type(8)));
typedef float  floatx4  __attribute__((ext_vector_type(4)));

#define DEVI static __device__ __forceinline__

constexpr int Bb = 4, Ss = 2048, Dd = 1024, Hh = 16, DHh = 64, DFFc = 4096;
constexpr int NTOK = Bb * Ss;   // 8192 rows
constexpr int NQKV = 3072;      // fused QKV width

// async global->LDS, 16B per lane. LDS dest: wave-uniform base + lane*16.
DEVI void gld_lds16(const void* g, void* l) {
  __builtin_amdgcn_global_load_lds(
      (const __attribute__((address_space(1))) void*)g,
      (__attribute__((address_space(3))) void*)l, 16, 0, 0);
}

DEVI float gelu_f(float x) {
  const float c = 0.7978845608028654f;  // sqrt(2/pi)
  float t = tanhf(c * (x + 0.044715f * x * x * x));
  return 0.5f * x * (1.0f + t);
}

// XCD-aware chunked block remap (T1). Valid only when nwg % 8 == 0.
DEVI int xcd_lin(int lin, int nwg) {
  return (lin & 7) * (nwg >> 3) + (lin >> 3);
}

// ---------------------------------------------------------------------------
// Cast 6 fp32 weight matrices to bf16 (one dispatch). grid.y selects tensor.
// ---------------------------------------------------------------------------
struct CastArgs {
  const float* src[6];
  bf16* dst[6];
  int n[6];
};
__global__ __launch_bounds__(256) void cast_w_kernel(CastArgs a) {
  const int which = blockIdx.y;
  const int idx = (blockIdx.x * 256 + threadIdx.x) * 4;
  if (idx >= a.n[which]) return;
  float4 v = *(const float4*)(a.src[which] + idx);
  bf16x4_t o = {(bf16)v.x, (bf16)v.y, (bf16)v.z, (bf16)v.w};
  *(bf16x4_t*)(a.dst[which] + idx) = o;
}

// ---------------------------------------------------------------------------
// LayerNorm: one block per row of D=1024.
// ---------------------------------------------------------------------------
template <typename TIN>
__global__ __launch_bounds__(256) void ln_kernel(const TIN* __restrict__ x,
                                                 const float* __restrict__ sc,
                                                 const float* __restrict__ sh,
                                                 bf16* __restrict__ out) {
  __shared__ float rs[4], rs2[4];
  const int row = blockIdx.x, t = threadIdx.x;
  const TIN* xr = x + (size_t)row * Dd;
  float v[4];
  if constexpr (sizeof(TIN) == 2) {
    bf16x4_t tmp = *(const bf16x4_t*)((const bf16*)xr + t * 4);
#pragma unroll
    for (int i = 0; i < 4; i++) v[i] = (float)tmp[i];
  } else {
    float4 tmp = *(const float4*)((const float*)xr + t * 4);
    v[0] = tmp.x; v[1] = tmp.y; v[2] = tmp.z; v[3] = tmp.w;
  }
  float s = v[0] + v[1] + v[2] + v[3];
  float s2 = v[0] * v[0] + v[1] * v[1] + v[2] * v[2] + v[3] * v[3];
#pragma unroll
  for (int off = 1; off < 64; off <<= 1) {
    s += __shfl_xor(s, off);
    s2 += __shfl_xor(s2, off);
  }
  if ((t & 63) == 0) { rs[t >> 6] = s; rs2[t >> 6] = s2; }
  __syncthreads();
  float S1 = rs[0] + rs[1] + rs[2] + rs[3];
  float S2 = rs2[0] + rs2[1] + rs2[2] + rs2[3];
  float mean = S1 * (1.0f / Dd);
  float var = S2 * (1.0f / Dd) - mean * mean;
  float rinv = rsqrtf(var + 1e-7f);
#pragma unroll
  for (int i = 0; i < 4; i++) {
    int c = t * 4 + i;
    out[(size_t)row * Dd + c] = (bf16)(((v[i] - mean) * rinv + sh[c]) * sc[c]);
  }
}

// ---------------------------------------------------------------------------
// Multi-block GEMM (m97-class + T2 + counted vmcnt): C = epi(A @ Bw^T).
// 128x128 tile, BK=32, 256 thr / 4 waves (2x2, 64x64 out each).
// TRIPLE-buffered LDS (48 KB -> 3 blocks/CU, 12 waves/CU): cross-BLOCK TLP
// hides barrier/LDS/latency stalls (m114) -- the lever both mega-block
// schedules (R5/R6, 1 block/CU lockstep, 630 TF) were missing.
// Stage tile t+2 into buf (t+2)%3 (not read during t, t+1); per-step
// vmcnt(4) keeps t+2's 4 loads in flight (T4); drain-0 only at tail.
// Swizzle for 64B rows: byte ^= ((row>>1)&3)<<4 (2-way conflicts = free),
// applied as inverse-swizzled global source + swizzled ds_read (rule 21).
// One s_barrier per K-step. No setprio (m190: negative on this class).
// MODE 0: bf16; 1: bf16 = f32 res+acc+bias; 2: bf16 = gelu(acc+b);
// MODE 3: f32 = bf16 res+acc+bias.
// ---------------------------------------------------------------------------
template <int MODE>
__global__ __launch_bounds__(256, 3) void gemmk(const bf16* __restrict__ A,
                                                const bf16* __restrict__ Bw,
                                                const float* __restrict__ bias,
                                                const void* __restrict__ res,
                                                void* __restrict__ outp,
                                                int M, int N, int K) {
  constexpr int TEL = 4096;                  // elems per (matrix, buffer): 128x32
  __shared__ bf16 lds[6 * TEL];              // 3 bufs x (A + B) = 48 KB
  bf16* Ab = lds;
  bf16* Bl = lds + 3 * TEL;

  const int tid = threadIdx.x;
  const int w = tid >> 6, lane = tid & 63;
  const int quad = lane >> 4, l16 = lane & 15;
  const int wr = w >> 1, wc = w & 1;

  const int gx = (int)gridDim.x;
  const int nwg = gx * (int)gridDim.y;
  const int lin = xcd_lin((int)blockIdx.y * gx + (int)blockIdx.x, nwg);
  const int m0 = (lin / gx) * 128;
  const int n0 = (lin % gx) * 128;

  // Staging geometry: pass p covers linear LDS bytes [p*4096 + tid*16).
  // Inverse-swizzle picks the global (row, col) so the linear write lands
  // swizzled: row = s>>6, colbyte = (s ^ (((row>>1)&3)<<4)) & 63.
  const bf16* Aps[2];
  const bf16* Bps[2];
#pragma unroll
  for (int p = 0; p < 2; ++p) {
    const int sp = p * 4096 + tid * 16;
    const int sr = sp >> 6;
    const int sc = ((sp ^ (((sr >> 1) & 3) << 4)) & 63) >> 1;
    Aps[p] = A + (size_t)(m0 + sr) * K + sc;
    Bps[p] = Bw + (size_t)(n0 + sr) * K + sc;
  }
  const int dst0 = w * 512 + lane * 8;  // elems, pass 0

  auto stage = [&](int t) {
    const int q = t % 3, ko = t * 32;
#pragma unroll
    for (int p = 0; p < 2; ++p) {
      gld_lds16(Aps[p] + ko, Ab + q * TEL + p * 2048 + dst0);
      gld_lds16(Bps[p] + ko, Bl + q * TEL + p * 2048 + dst0);
    }
  };
  auto rdA = [&](int q, int mi) {
    const int r = wr * 64 + mi * 16 + l16;
    return *(const bf16x8_t*)(Ab + q * TEL + r * 32 +
                              ((quad * 8) ^ (((r >> 1) & 3) << 3)));
  };
  auto rdB = [&](int q, int j) {
    const int r = wc * 64 + j * 16 + l16;
    return *(const bf16x8_t*)(Bl + q * TEL + r * 32 +
                              ((quad * 8) ^ (((r >> 1) & 3) << 3)));
  };

  floatx4 acc[4][4] = {};
  const int NT = K >> 5;

  stage(0);
  stage(1);
  asm volatile("s_waitcnt vmcnt(4)" ::: "memory");  // tile 0 resident
  __builtin_amdgcn_sched_barrier(0);
  __builtin_amdgcn_s_barrier();

  for (int t = 0; t < NT; ++t) {
    const int q = t % 3;
    bf16x8_t a[4], b[4];
#pragma unroll
    for (int mi = 0; mi < 4; ++mi) a[mi] = rdA(q, mi);
#pragma unroll
    for (int j = 0; j < 4; ++j) b[j] = rdB(q, j);
    if (t + 2 < NT) stage(t + 2);  // buf (t+2)%3: idle during t, t+1
#pragma unroll
    for (int mi = 0; mi < 4; ++mi)
#pragma unroll
      for (int j = 0; j < 4; ++j)
        acc[mi][j] = __builtin_amdgcn_mfma_f32_16x16x32_bf16(a[mi], b[j],
                                                             acc[mi][j], 0, 0, 0);
    // counted wait: tile t+1 resident, tile t+2's 4 loads stay in flight.
    if (t + 2 < NT) {
      asm volatile("s_waitcnt vmcnt(4)" ::: "memory");
    } else {
      asm volatile("s_waitcnt vmcnt(0)" ::: "memory");
    }
    __builtin_amdgcn_sched_barrier(0);
    __builtin_amdgcn_s_barrier();
  }

  // epilogue: C/D layout col=lane&15, row=quad*4+reg
#pragma unroll
  for (int i = 0; i < 4; ++i) {
    const int rbase = m0 + wr * 64 + i * 16 + quad * 4;
#pragma unroll
    for (int j2 = 0; j2 < 4; ++j2) {
      const int col = n0 + wc * 64 + j2 * 16 + l16;
      float bv = 0.f;
      if constexpr (MODE == 1 || MODE == 2 || MODE == 3) bv = bias[col];
#pragma unroll
      for (int r = 0; r < 4; ++r) {
        const int row = rbase + r;
        float vacc = acc[i][j2][r] + bv;
        if constexpr (MODE == 0) {
          ((bf16*)outp)[(size_t)row * N + col] = (bf16)vacc;
        } else if constexpr (MODE == 1) {
          float xres = ((const float*)res)[(size_t)row * N + col];
          ((bf16*)outp)[(size_t)row * N + col] = (bf16)(xres + vacc);
        } else if constexpr (MODE == 2) {
          ((bf16*)outp)[(size_t)row * N + col] = (bf16)gelu_f(vacc);
        } else {
          float xres = (float)((const bf16*)res)[(size_t)row * N + col];
          ((float*)outp)[(size_t)row * N + col] = xres + vacc;
        }
      }
    }
  }
}

// ---------------------------------------------------------------------------
// Dual-chain causal flash attention (unchanged from verified R5/R6).
// ---------------------------------------------------------------------------
__global__ __launch_bounds__(256) void attn_kernel(const bf16* __restrict__ QKV,
                                                   bf16* __restrict__ ctx) {
  __shared__ bf16 Ks[64 * 72];        // [key][dh]
  __shared__ bf16 Vt[64 * 72];        // [dh][key]
  __shared__ bf16 Ps[4][2][16 * 72];  // per-wave, per-chain P [q][key]

  const int tid = threadIdx.x;
  const int wave = tid >> 6, lane = tid & 63;
  const int quad = lane >> 4, l16 = lane & 15;
  const int lin = xcd_lin((int)blockIdx.y * 8 + (int)blockIdx.x, 8 * Bb * Hh);
  const int gsel = lin & 7;
  const int bh = lin >> 3;
  const int bsel = bh >> 4, hsel = bh & 15;
  const size_t base = ((size_t)bsel * Ss) * NQKV + (size_t)hsel * 64;
  const bf16* Qp = QKV + base;
  const bf16* Kp = QKV + base + 1024;
  const bf16* Vp = QKV + base + 2048;

  const int kr0 = tid >> 3, kc0 = (tid & 7) * 8;  // K staging
  const int vp2 = tid & 31, vs = tid >> 5;        // V staging

  for (int pass = 0; pass < 2; ++pass) {
    const int g2 = (pass == 0) ? gsel : 15 - gsel;
    const int tA = 2 * g2, tB = tA + 1;
    const int q0A = tA * 64, q0B = q0A + 64;

    const int qrA = q0A + wave * 16 + l16;
    const int qrB = q0B + wave * 16 + l16;
    bf16x8_t qA0 = *(const bf16x8_t*)(Qp + (size_t)qrA * NQKV + quad * 8);
    bf16x8_t qA1 = *(const bf16x8_t*)(Qp + (size_t)qrA * NQKV + 32 + quad * 8);
    bf16x8_t qB0 = *(const bf16x8_t*)(Qp + (size_t)qrB * NQKV + quad * 8);
    bf16x8_t qB1 = *(const bf16x8_t*)(Qp + (size_t)qrB * NQKV + 32 + quad * 8);
#pragma unroll
    for (int i = 0; i < 8; i++) {
      qA0[i] = (bf16)((float)qA0[i] * 0.125f);
      qA1[i] = (bf16)((float)qA1[i] * 0.125f);
      qB0[i] = (bf16)((float)qB0[i] * 0.125f);
      qB1[i] = (bf16)((float)qB1[i] * 0.125f);
    }

    floatx4 oA[4] = {}, oB[4] = {};
    float lA[4] = {0.f, 0.f, 0.f, 0.f}, lB[4] = {0.f, 0.f, 0.f, 0.f};

    {
      bf16x8_t k0 = *(const bf16x8_t*)(Kp + (size_t)kr0 * NQKV + kc0);
      bf16x8_t k1 = *(const bf16x8_t*)(Kp + (size_t)(kr0 + 32) * NQKV + kc0);
      const bf16* v0p = Vp + (size_t)(2 * vp2) * NQKV + vs * 8;
      bf16x8_t va = *(const bf16x8_t*)(v0p);
      bf16x8_t vb = *(const bf16x8_t*)(v0p + NQKV);
      *(bf16x8_t*)(Ks + kr0 * 72 + kc0) = k0;
      *(bf16x8_t*)(Ks + (kr0 + 32) * 72 + kc0) = k1;
#pragma unroll
      for (int i = 0; i < 8; i++) {
        bf16x2_t p2 = {va[i], vb[i]};
        *(bf16x2_t*)(Vt + (vs * 8 + i) * 72 + 2 * vp2) = p2;
      }
      __syncthreads();
    }

    auto do_sm = [&](floatx4* sg, float* l_i, bf16* pw, int q0c, bool diag,
                     int kc) {
      if (diag) {
#pragma unroll
        for (int r = 0; r < 4; r++) {
          const int rq = q0c + wave * 16 + quad * 4 + r;
          float p[4];
          float rsum = 0.f;
#pragma unroll
          for (int g = 0; g < 4; g++) {
            float v = (kc + g * 16 + l16 > rq) ? -1e30f : sg[g][r];
            p[g] = __expf(v);
            rsum += p[g];
          }
          rsum += __shfl_xor(rsum, 1);
          rsum += __shfl_xor(rsum, 2);
          rsum += __shfl_xor(rsum, 4);
          rsum += __shfl_xor(rsum, 8);
          l_i[r] += rsum;
#pragma unroll
          for (int g = 0; g < 4; g++)
            pw[(quad * 4 + r) * 72 + g * 16 + l16] = (bf16)p[g];
        }
      } else {
#pragma unroll
        for (int r = 0; r < 4; r++) {
          float p[4];
          float rsum = 0.f;
#pragma unroll
          for (int g = 0; g < 4; g++) {
            p[g] = __expf(sg[g][r]);
            rsum += p[g];
          }
          rsum += __shfl_xor(rsum, 1);
          rsum += __shfl_xor(rsum, 2);
          rsum += __shfl_xor(rsum, 4);
          rsum += __shfl_xor(rsum, 8);
          l_i[r] += rsum;
#pragma unroll
          for (int g = 0; g < 4; g++)
            pw[(quad * 4 + r) * 72 + g * 16 + l16] = (bf16)p[g];
        }
      }
    };

    const int ntiles = tB + 1;
    for (int it = 0; it < ntiles; ++it) {
      const int kc = it * 64;
      const bool more = (it + 1) < ntiles;
      const bool aAct = (it <= tA);  // block-uniform

      bf16x8_t nk0, nk1, nva, nvb;
      if (more) {
        const int kn = kc + 64;
        nk0 = *(const bf16x8_t*)(Kp + (size_t)(kn + kr0) * NQKV + kc0);
        nk1 = *(const bf16x8_t*)(Kp + (size_t)(kn + kr0 + 32) * NQKV + kc0);
        const bf16* v0p = Vp + (size_t)(kn + 2 * vp2) * NQKV + vs * 8;
        nva = *(const bf16x8_t*)(v0p);
        nvb = *(const bf16x8_t*)(v0p + NQKV);
      }

      floatx4 sA[4], sB[4];
      __builtin_amdgcn_s_setprio(1);
#pragma unroll
      for (int g = 0; g < 4; g++) {
        bf16x8_t ka = *(const bf16x8_t*)(Ks + (g * 16 + l16) * 72 + quad * 8);
        bf16x8_t kb = *(const bf16x8_t*)(Ks + (g * 16 + l16) * 72 + 32 + quad * 8);
        floatx4 z = {0.f, 0.f, 0.f, 0.f};
        if (aAct) {
          floatx4 s = __builtin_amdgcn_mfma_f32_16x16x32_bf16(qA0, ka, z, 0, 0, 0);
          sA[g] = __builtin_amdgcn_mfma_f32_16x16x32_bf16(qA1, kb, s, 0, 0, 0);
        }
        floatx4 s2 = __builtin_amdgcn_mfma_f32_16x16x32_bf16(qB0, ka, z, 0, 0, 0);
        sB[g] = __builtin_amdgcn_mfma_f32_16x16x32_bf16(qB1, kb, s2, 0, 0, 0);
      }
      __builtin_amdgcn_s_setprio(0);

      if (aAct) do_sm(sA, lA, &Ps[wave][0][0], q0A, it == tA, kc);
      do_sm(sB, lB, &Ps[wave][1][0], q0B, it == tB, kc);

      bf16x8_t pA0, pA1;
      if (aAct) {
        pA0 = *(const bf16x8_t*)(&Ps[wave][0][0] + l16 * 72 + quad * 8);
        pA1 = *(const bf16x8_t*)(&Ps[wave][0][0] + l16 * 72 + 32 + quad * 8);
      }
      bf16x8_t pB0 = *(const bf16x8_t*)(&Ps[wave][1][0] + l16 * 72 + quad * 8);
      bf16x8_t pB1 = *(const bf16x8_t*)(&Ps[wave][1][0] + l16 * 72 + 32 + quad * 8);
      __builtin_amdgcn_s_setprio(1);
#pragma unroll
      for (int nt = 0; nt < 4; nt++) {
        bf16x8_t vf0 = *(const bf16x8_t*)(Vt + (nt * 16 + l16) * 72 + quad * 8);
        bf16x8_t vf1 = *(const bf16x8_t*)(Vt + (nt * 16 + l16) * 72 + 32 + quad * 8);
        if (aAct) {
          oA[nt] = __builtin_amdgcn_mfma_f32_16x16x32_bf16(pA0, vf0, oA[nt], 0, 0, 0);
          oA[nt] = __builtin_amdgcn_mfma_f32_16x16x32_bf16(pA1, vf1, oA[nt], 0, 0, 0);
        }
        oB[nt] = __builtin_amdgcn_mfma_f32_16x16x32_bf16(pB0, vf0, oB[nt], 0, 0, 0);
        oB[nt] = __builtin_amdgcn_mfma_f32_16x16x32_bf16(pB1, vf1, oB[nt], 0, 0, 0);
      }
      __builtin_amdgcn_s_setprio(0);

      __syncthreads();
      if (more) {
        *(bf16x8_t*)(Ks + kr0 * 72 + kc0) = nk0;
        *(bf16x8_t*)(Ks + (kr0 + 32) * 72 + kc0) = nk1;
#pragma unroll
        for (int i = 0; i < 8; i++) {
          bf16x2_t p2 = {nva[i], nvb[i]};
          *(bf16x2_t*)(Vt + (vs * 8 + i) * 72 + 2 * vp2) = p2;
        }
        __syncthreads();
      }
    }

#pragma unroll
    for (int nt = 0; nt < 4; nt++)
#pragma unroll
      for (int r = 0; r < 4; r++) {
        const int rqA = q0A + wave * 16 + quad * 4 + r;
        const int rqB = q0B + wave * 16 + quad * 4 + r;
        size_t aa = ((size_t)bsel * Ss + rqA) * Dd + (size_t)hsel * DHh + nt * 16 + l16;
        size_t ab = ((size_t)bsel * Ss + rqB) * Dd + (size_t)hsel * DHh + nt * 16 + l16;
        ctx[aa] = (bf16)(oA[nt][r] / lA[r]);
        ctx[ab] = (bf16)(oB[nt][r] / lB[r]);
      }
  }
}

// ---------------------------------------------------------------------------
extern "C" void kernel_launch(void* const* d_in, const int* in_sizes, int n_in,
                              void* d_out, int out_size, void* d_ws, size_t ws_size,
                              hipStream_t stream) {
  (void)in_sizes; (void)n_in; (void)out_size; (void)ws_size;
  const float* x = (const float*)d_in[0];
  const float* Wq = (const float*)d_in[1];
  const float* Wk = (const float*)d_in[2];
  const float* Wv = (const float*)d_in[3];
  const float* Wo = (const float*)d_in[4];
  const float* bo = (const float*)d_in[5];
  const float* W1 = (const float*)d_in[6];
  const float* b1 = (const float*)d_in[7];
  const float* W2 = (const float*)d_in[8];
  const float* b2 = (const float*)d_in[9];
  const float* ln1s = (const float*)d_in[10];
  const float* ln1b = (const float*)d_in[11];
  const float* ln2s = (const float*)d_in[12];
  const float* ln2b = (const float*)d_in[13];

  char* wsb = (char*)d_ws;
  const size_t MB = 1024 * 1024;
  bf16* Wqb = (bf16*)(wsb);
  bf16* Wkb = (bf16*)(wsb + 2 * MB);
  bf16* Wvb = (bf16*)(wsb + 4 * MB);
  bf16* Wob = (bf16*)(wsb + 6 * MB);
  bf16* W1b = (bf16*)(wsb + 8 * MB);
  bf16* W2b = (bf16*)(wsb + 16 * MB);
  bf16* h   = (bf16*)(wsb + 24 * MB);
  bf16* qkv = (bf16*)(wsb + 40 * MB);  // 48MB: 8192 x 3072 row-major [Q|K|V]
  bf16* ctx = (bf16*)(wsb + 88 * MB);
  bf16* x1  = (bf16*)(wsb + 104 * MB);
  bf16* h2  = ctx;
  bf16* ff1 = h;

  dim3 blk(256, 1, 1);

  CastArgs ca;
  ca.src[0] = Wq; ca.src[1] = Wk; ca.src[2] = Wv; ca.src[3] = Wo;
  ca.src[4] = W1; ca.src[5] = W2;
  ca.dst[0] = Wqb; ca.dst[1] = Wkb; ca.dst[2] = Wvb; ca.dst[3] = Wob;
  ca.dst[4] = W1b; ca.dst[5] = W2b;
  ca.n[0] = ca.n[1] = ca.n[2] = ca.n[3] = Dd * Dd;
  ca.n[4] = ca.n[5] = Dd * DFFc;
  cast_w_kernel<<<dim3((Dd * DFFc) / (256 * 4), 6, 1), blk, 0, stream>>>(ca);

  ln_kernel<float><<<dim3(NTOK, 1, 1), blk, 0, stream>>>(x, ln1s, ln1b, h);
  // QKV: M=8192, N=3072, K=1024 -> grid (24, 64) = 1536 blocks.
  gemmk<0><<<dim3(24, NTOK / 128, 1), blk, 0, stream>>>(h, Wqb, nullptr, nullptr,
                                                        qkv, NTOK, NQKV, Dd);
  // dual-chain attn: grid (8, 64) = 512 blocks, balanced 34 slots each.
  attn_kernel<<<dim3(8, Bb * Hh, 1), blk, 0, stream>>>(qkv, ctx);
  // Wo: N=1024 -> grid (8, 64) = 512 blocks.
  gemmk<1><<<dim3(8, NTOK / 128, 1), blk, 0, stream>>>(ctx, Wob, bo, x, x1,
                                                       NTOK, Dd, Dd);
  ln_kernel<bf16><<<dim3(NTOK, 1, 1), blk, 0, stream>>>(x1, ln2s, ln2b, h2);
  // FF1: N=4096 -> grid (32, 64) = 2048 blocks.
  gemmk<2><<<dim3(32, NTOK / 128, 1), blk, 0, stream>>>(h2, W1b, b1, nullptr, ff1,
                                                        NTOK, DFFc, Dd);
  // FF2: N=1024, K=4096 -> grid (8, 64) = 512 blocks.
  gemmk<3><<<dim3(8, NTOK / 128, 1), blk, 0, stream>>>(ff1, W2b, b2, x1,
                                                       (float*)d_out, NTOK, Dd, DFFc);
}

// Round 8
// 467.170 us; speedup vs baseline: 1.0984x; 1.0984x over previous
//
#include <hip/hip_runtime.h>
#include <hip/hip_bf16.h>
#include <math.h>

typedef __bf16 bf16;
typedef __bf16 bf16x2_t __attribute__((ext_vector_type(2)));
typedef __bf16 bf16x4_t __attribute__((ext_vector_type(4)));
typedef __bf16 bf16x8_t __attribute__((ext_vector_type(8)));
typedef float  floatx4  __attribute__((ext_vector_type(4)));

#define DEVI static __device__ __forceinline__

constexpr int Bb = 4, Ss = 2048, Dd = 1024, Hh = 16, DHh = 64, DFFc = 4096;
constexpr int NTOK = Bb * Ss;   // 8192 rows
constexpr int NQKV = 3072;      // fused QKV width

// async global->LDS, 16B per lane. LDS dest: wave-uniform base + lane*16.
DEVI void gld_lds16(const void* g, void* l) {
  __builtin_amdgcn_global_load_lds(
      (const __attribute__((address_space(1))) void*)g,
      (__attribute__((address_space(3))) void*)l, 16, 0, 0);
}

// gelu via exp-based tanh: tanh(z) = 1 - 2/(e^{2z}+1). ~6 VALU ops vs the
// long libm tanhf polynomial (VALUBusy 44% > MfmaUtil 26% in R5/R6 -> VALU
// is the busier pipe; epilogue tanhf was part of that). err ~1e-7 << bf16 ulp.
DEVI float gelu_f(float x) {
  const float c = 0.7978845608028654f;  // sqrt(2/pi)
  float z = c * (x + 0.044715f * x * x * x);
  float t = 1.0f - 2.0f / (__expf(2.0f * z) + 1.0f);
  return 0.5f * x * (1.0f + t);
}

// XCD-aware chunked block remap (T1). Valid only when nwg % 8 == 0.
DEVI int xcd_lin(int lin, int nwg) {
  return (lin & 7) * (nwg >> 3) + (lin >> 3);
}

// ---------------------------------------------------------------------------
// Cast 6 fp32 weight matrices to bf16 (one dispatch). grid.y selects tensor.
// ---------------------------------------------------------------------------
struct CastArgs {
  const float* src[6];
  bf16* dst[6];
  int n[6];
};
__global__ __launch_bounds__(256) void cast_w_kernel(CastArgs a) {
  const int which = blockIdx.y;
  const int idx = (blockIdx.x * 256 + threadIdx.x) * 4;
  if (idx >= a.n[which]) return;
  float4 v = *(const float4*)(a.src[which] + idx);
  bf16x4_t o = {(bf16)v.x, (bf16)v.y, (bf16)v.z, (bf16)v.w};
  *(bf16x4_t*)(a.dst[which] + idx) = o;
}

// ---------------------------------------------------------------------------
// LayerNorm: one block per row of D=1024.
// ---------------------------------------------------------------------------
template <typename TIN>
__global__ __launch_bounds__(256) void ln_kernel(const TIN* __restrict__ x,
                                                 const float* __restrict__ sc,
                                                 const float* __restrict__ sh,
                                                 bf16* __restrict__ out) {
  __shared__ float rs[4], rs2[4];
  const int row = blockIdx.x, t = threadIdx.x;
  const TIN* xr = x + (size_t)row * Dd;
  float v[4];
  if constexpr (sizeof(TIN) == 2) {
    bf16x4_t tmp = *(const bf16x4_t*)((const bf16*)xr + t * 4);
#pragma unroll
    for (int i = 0; i < 4; i++) v[i] = (float)tmp[i];
  } else {
    float4 tmp = *(const float4*)((const float*)xr + t * 4);
    v[0] = tmp.x; v[1] = tmp.y; v[2] = tmp.z; v[3] = tmp.w;
  }
  float s = v[0] + v[1] + v[2] + v[3];
  float s2 = v[0] * v[0] + v[1] * v[1] + v[2] * v[2] + v[3] * v[3];
#pragma unroll
  for (int off = 1; off < 64; off <<= 1) {
    s += __shfl_xor(s, off);
    s2 += __shfl_xor(s2, off);
  }
  if ((t & 63) == 0) { rs[t >> 6] = s; rs2[t >> 6] = s2; }
  __syncthreads();
  float S1 = rs[0] + rs[1] + rs[2] + rs[3];
  float S2 = rs2[0] + rs2[1] + rs2[2] + rs2[3];
  float mean = S1 * (1.0f / Dd);
  float var = S2 * (1.0f / Dd) - mean * mean;
  float rinv = rsqrtf(var + 1e-7f);
#pragma unroll
  for (int i = 0; i < 4; i++) {
    int c = t * 4 + i;
    out[(size_t)row * Dd + c] = (bf16)(((v[i] - mean) * rinv + sh[c]) * sc[c]);
  }
}

// ---------------------------------------------------------------------------
// 256-row multi-phase GEMM (verified R5 structure -- best measured: 630 TF
// FF1, 493 us total). BM=256, BK=64, 512 thr / 8 waves, double-buffered LDS
// (parity), staggered half-tile staging, counted vmcnt(4)/(2) at tile end,
// XOR swizzle via inverse-swizzled global source (0 conflicts measured).
// BN=256: waves 2x4, per-wave 128x64, 4 phases. BN=128: waves 4x2, 64x64,
// 2 phases. R7's 128^2 multi-block experiment REFUTED the occupancy theory
// (484 TF, FETCH 181MB vs 74MB): the 256-row tile's arithmetic intensity
// beats cross-block TLP here. Do not shrink the tile.
// ---------------------------------------------------------------------------
template <int BN, int MODE>
__global__ __launch_bounds__(512, 2) void gemmk(const bf16* __restrict__ A,
                                                const bf16* __restrict__ Bw,
                                                const float* __restrict__ bias,
                                                const void* __restrict__ res,
                                                void* __restrict__ outp,
                                                int M, int N, int K) {
  constexpr int BUNITS = BN / 64;               // 64-row units in B tile
  constexpr int AELEM = 16384;                  // 256x64 elems
  constexpr int BELEM = BUNITS * 4096;
  constexpr int WN = (BN == 256) ? 4 : 2;
  constexpr int WM = 8 / WN;
  constexpr int WR_H = 256 / WM;                // 128 or 64
  constexpr int M_rep = WR_H / 16;              // 8 or 4
  constexpr int NPH = M_rep / 2;                // 4 or 2
  __shared__ bf16 lds[2 * (AELEM + BELEM)];     // 128 KB or 96 KB
  bf16* Ab = lds;
  bf16* Bl = lds + 2 * AELEM;

  const int tid = threadIdx.x;
  const int w = tid >> 6, lane = tid & 63;
  const int quad = lane >> 4, l16 = lane & 15;
  const int l7x8 = (lane & 7) << 3;             // read-side swizzle (elems)
  const int wr = w / WN, wc = w % WN;

  const int gx = (int)gridDim.x;
  const int nwg = gx * (int)gridDim.y;
  const int lin = xcd_lin((int)blockIdx.y * gx + (int)blockIdx.x, nwg);
  const int m0 = (lin / gx) * 256;
  const int n0 = (lin % gx) * BN;

  const int s0 = w * 1024 + lane * 16;
  const int sr = s0 >> 7;                              // row 0..63
  const int sc = ((s0 ^ ((sr & 7) << 4)) & 127) >> 1;  // col element
  const int toff = w * 512 + lane * 8;                 // elem offset in unit

  const bf16* Agu[4];
  const bf16* Bgu[BUNITS];
#pragma unroll
  for (int u = 0; u < 4; ++u) Agu[u] = A + (size_t)(m0 + u * 64 + sr) * K + sc;
#pragma unroll
  for (int u = 0; u < BUNITS; ++u)
    Bgu[u] = Bw + (size_t)(n0 + u * 64 + sr) * K + sc;

  auto issA = [&](int t, int lo) {
    const int q = t & 1, ko = t * 64;
#pragma unroll
    for (int u = 0; u < 2; ++u)
      gld_lds16(Agu[lo + u] + ko, Ab + q * AELEM + (lo + u) * 4096 + toff);
  };
  auto issB = [&](int t, int lo, int cnt) {
    const int q = t & 1, ko = t * 64;
#pragma unroll 2
    for (int u = 0; u < cnt; ++u)
      gld_lds16(Bgu[lo + u] + ko, Bl + q * BELEM + (lo + u) * 4096 + toff);
  };

  auto rdA = [&](int q, int mi, int kk) {
    const int r = wr * WR_H + mi * 16 + l16;
    return *(const bf16x8_t*)(Ab + q * AELEM + (r >> 6) * 4096 + (r & 63) * 64 +
                              ((quad * 8 + kk * 32) ^ l7x8));
  };
  auto rdB = [&](int q, int j, int kk) {
    const int r = wc * 64 + j * 16 + l16;
    return *(const bf16x8_t*)(Bl + q * BELEM + (r >> 6) * 4096 + (r & 63) * 64 +
                              ((quad * 8 + kk * 32) ^ l7x8));
  };

  floatx4 acc[M_rep][4] = {};
  const int NT = K >> 6;

  issA(0, 0); issA(0, 2); issB(0, 0, BUNITS);
  issA(1, 0);
  if (BN == 256) {
    issB(1, 0, 2);
    asm volatile("s_waitcnt vmcnt(4)" ::: "memory");
  } else {
    asm volatile("s_waitcnt vmcnt(2)" ::: "memory");
  }
  __builtin_amdgcn_sched_barrier(0);
  __builtin_amdgcn_s_barrier();
  __builtin_amdgcn_sched_barrier(0);

  for (int t = 0; t < NT; ++t) {
    const int q = t & 1;
    bf16x8_t bfv[4][2];
#pragma unroll
    for (int p = 0; p < NPH; ++p) {
      bf16x8_t af[2][2];
#pragma unroll
      for (int im = 0; im < 2; ++im)
#pragma unroll
        for (int kk = 0; kk < 2; ++kk)
          af[im][kk] = rdA(q, p * 2 + im, kk);
      if (p == 0) {
#pragma unroll
        for (int j = 0; j < 4; ++j)
#pragma unroll
          for (int kk = 0; kk < 2; ++kk)
            bfv[j][kk] = rdB(q, j, kk);
        if (t + 1 < NT) {
          issA(t + 1, 2);
          if (BN == 256) issB(t + 1, 2, 2);
          else issB(t + 1, 0, 2);
        }
      }
      __builtin_amdgcn_s_barrier();
      __builtin_amdgcn_sched_barrier(0);
      __builtin_amdgcn_s_setprio(1);
#pragma unroll
      for (int im = 0; im < 2; ++im)
#pragma unroll
        for (int j = 0; j < 4; ++j)
#pragma unroll
          for (int kk = 0; kk < 2; ++kk)
            acc[p * 2 + im][j] = __builtin_amdgcn_mfma_f32_16x16x32_bf16(
                af[im][kk], bfv[j][kk], acc[p * 2 + im][j], 0, 0, 0);
      __builtin_amdgcn_s_setprio(0);
      if (p == NPH - 1) {
        if (t + 2 < NT) {
          issA(t + 2, 0);
          if (BN == 256) issB(t + 2, 0, 2);
          if (BN == 256) asm volatile("s_waitcnt vmcnt(4)" ::: "memory");
          else           asm volatile("s_waitcnt vmcnt(2)" ::: "memory");
        } else {
          asm volatile("s_waitcnt vmcnt(0)" ::: "memory");
        }
        __builtin_amdgcn_sched_barrier(0);
      }
      __builtin_amdgcn_s_barrier();
      __builtin_amdgcn_sched_barrier(0);
    }
  }

  // epilogue: C/D layout col=lane&15, row=quad*4+reg
#pragma unroll
  for (int i = 0; i < M_rep; ++i) {
    const int rbase = m0 + wr * WR_H + i * 16 + quad * 4;
#pragma unroll
    for (int j2 = 0; j2 < 4; ++j2) {
      const int col = n0 + wc * 64 + j2 * 16 + l16;
      float bv = 0.f;
      if constexpr (MODE == 1 || MODE == 2 || MODE == 3) bv = bias[col];
#pragma unroll
      for (int r = 0; r < 4; ++r) {
        const int row = rbase + r;
        float vacc = acc[i][j2][r] + bv;
        if constexpr (MODE == 0) {
          ((bf16*)outp)[(size_t)row * N + col] = (bf16)vacc;
        } else if constexpr (MODE == 1) {
          float xres = ((const float*)res)[(size_t)row * N + col];
          ((bf16*)outp)[(size_t)row * N + col] = (bf16)(xres + vacc);
        } else if constexpr (MODE == 2) {
          ((bf16*)outp)[(size_t)row * N + col] = (bf16)gelu_f(vacc);
        } else {
          float xres = (float)((const bf16*)res)[(size_t)row * N + col];
          ((float*)outp)[(size_t)row * N + col] = xres + vacc;
        }
      }
    }
  }
}

// ---------------------------------------------------------------------------
// Dual-chain causal flash attention (unchanged from verified R5).
// ---------------------------------------------------------------------------
__global__ __launch_bounds__(256) void attn_kernel(const bf16* __restrict__ QKV,
                                                   bf16* __restrict__ ctx) {
  __shared__ bf16 Ks[64 * 72];        // [key][dh]
  __shared__ bf16 Vt[64 * 72];        // [dh][key]
  __shared__ bf16 Ps[4][2][16 * 72];  // per-wave, per-chain P [q][key]

  const int tid = threadIdx.x;
  const int wave = tid >> 6, lane = tid & 63;
  const int quad = lane >> 4, l16 = lane & 15;
  const int lin = xcd_lin((int)blockIdx.y * 8 + (int)blockIdx.x, 8 * Bb * Hh);
  const int gsel = lin & 7;
  const int bh = lin >> 3;
  const int bsel = bh >> 4, hsel = bh & 15;
  const size_t base = ((size_t)bsel * Ss) * NQKV + (size_t)hsel * 64;
  const bf16* Qp = QKV + base;
  const bf16* Kp = QKV + base + 1024;
  const bf16* Vp = QKV + base + 2048;

  const int kr0 = tid >> 3, kc0 = (tid & 7) * 8;  // K staging
  const int vp2 = tid & 31, vs = tid >> 5;        // V staging

  for (int pass = 0; pass < 2; ++pass) {
    const int g2 = (pass == 0) ? gsel : 15 - gsel;
    const int tA = 2 * g2, tB = tA + 1;
    const int q0A = tA * 64, q0B = q0A + 64;

    const int qrA = q0A + wave * 16 + l16;
    const int qrB = q0B + wave * 16 + l16;
    bf16x8_t qA0 = *(const bf16x8_t*)(Qp + (size_t)qrA * NQKV + quad * 8);
    bf16x8_t qA1 = *(const bf16x8_t*)(Qp + (size_t)qrA * NQKV + 32 + quad * 8);
    bf16x8_t qB0 = *(const bf16x8_t*)(Qp + (size_t)qrB * NQKV + quad * 8);
    bf16x8_t qB1 = *(const bf16x8_t*)(Qp + (size_t)qrB * NQKV + 32 + quad * 8);
#pragma unroll
    for (int i = 0; i < 8; i++) {
      qA0[i] = (bf16)((float)qA0[i] * 0.125f);
      qA1[i] = (bf16)((float)qA1[i] * 0.125f);
      qB0[i] = (bf16)((float)qB0[i] * 0.125f);
      qB1[i] = (bf16)((float)qB1[i] * 0.125f);
    }

    floatx4 oA[4] = {}, oB[4] = {};
    float lA[4] = {0.f, 0.f, 0.f, 0.f}, lB[4] = {0.f, 0.f, 0.f, 0.f};

    {
      bf16x8_t k0 = *(const bf16x8_t*)(Kp + (size_t)kr0 * NQKV + kc0);
      bf16x8_t k1 = *(const bf16x8_t*)(Kp + (size_t)(kr0 + 32) * NQKV + kc0);
      const bf16* v0p = Vp + (size_t)(2 * vp2) * NQKV + vs * 8;
      bf16x8_t va = *(const bf16x8_t*)(v0p);
      bf16x8_t vb = *(const bf16x8_t*)(v0p + NQKV);
      *(bf16x8_t*)(Ks + kr0 * 72 + kc0) = k0;
      *(bf16x8_t*)(Ks + (kr0 + 32) * 72 + kc0) = k1;
#pragma unroll
      for (int i = 0; i < 8; i++) {
        bf16x2_t p2 = {va[i], vb[i]};
        *(bf16x2_t*)(Vt + (vs * 8 + i) * 72 + 2 * vp2) = p2;
      }
      __syncthreads();
    }

    auto do_sm = [&](floatx4* sg, float* l_i, bf16* pw, int q0c, bool diag,
                     int kc) {
      if (diag) {
#pragma unroll
        for (int r = 0; r < 4; r++) {
          const int rq = q0c + wave * 16 + quad * 4 + r;
          float p[4];
          float rsum = 0.f;
#pragma unroll
          for (int g = 0; g < 4; g++) {
            float v = (kc + g * 16 + l16 > rq) ? -1e30f : sg[g][r];
            p[g] = __expf(v);
            rsum += p[g];
          }
          rsum += __shfl_xor(rsum, 1);
          rsum += __shfl_xor(rsum, 2);
          rsum += __shfl_xor(rsum, 4);
          rsum += __shfl_xor(rsum, 8);
          l_i[r] += rsum;
#pragma unroll
          for (int g = 0; g < 4; g++)
            pw[(quad * 4 + r) * 72 + g * 16 + l16] = (bf16)p[g];
        }
      } else {
#pragma unroll
        for (int r = 0; r < 4; r++) {
          float p[4];
          float rsum = 0.f;
#pragma unroll
          for (int g = 0; g < 4; g++) {
            p[g] = __expf(sg[g][r]);
            rsum += p[g];
          }
          rsum += __shfl_xor(rsum, 1);
          rsum += __shfl_xor(rsum, 2);
          rsum += __shfl_xor(rsum, 4);
          rsum += __shfl_xor(rsum, 8);
          l_i[r] += rsum;
#pragma unroll
          for (int g = 0; g < 4; g++)
            pw[(quad * 4 + r) * 72 + g * 16 + l16] = (bf16)p[g];
        }
      }
    };

    const int ntiles = tB + 1;
    for (int it = 0; it < ntiles; ++it) {
      const int kc = it * 64;
      const bool more = (it + 1) < ntiles;
      const bool aAct = (it <= tA);  // block-uniform

      bf16x8_t nk0, nk1, nva, nvb;
      if (more) {
        const int kn = kc + 64;
        nk0 = *(const bf16x8_t*)(Kp + (size_t)(kn + kr0) * NQKV + kc0);
        nk1 = *(const bf16x8_t*)(Kp + (size_t)(kn + kr0 + 32) * NQKV + kc0);
        const bf16* v0p = Vp + (size_t)(kn + 2 * vp2) * NQKV + vs * 8;
        nva = *(const bf16x8_t*)(v0p);
        nvb = *(const bf16x8_t*)(v0p + NQKV);
      }

      floatx4 sA[4], sB[4];
      __builtin_amdgcn_s_setprio(1);
#pragma unroll
      for (int g = 0; g < 4; g++) {
        bf16x8_t ka = *(const bf16x8_t*)(Ks + (g * 16 + l16) * 72 + quad * 8);
        bf16x8_t kb = *(const bf16x8_t*)(Ks + (g * 16 + l16) * 72 + 32 + quad * 8);
        floatx4 z = {0.f, 0.f, 0.f, 0.f};
        if (aAct) {
          floatx4 s = __builtin_amdgcn_mfma_f32_16x16x32_bf16(qA0, ka, z, 0, 0, 0);
          sA[g] = __builtin_amdgcn_mfma_f32_16x16x32_bf16(qA1, kb, s, 0, 0, 0);
        }
        floatx4 s2 = __builtin_amdgcn_mfma_f32_16x16x32_bf16(qB0, ka, z, 0, 0, 0);
        sB[g] = __builtin_amdgcn_mfma_f32_16x16x32_bf16(qB1, kb, s2, 0, 0, 0);
      }
      __builtin_amdgcn_s_setprio(0);

      if (aAct) do_sm(sA, lA, &Ps[wave][0][0], q0A, it == tA, kc);
      do_sm(sB, lB, &Ps[wave][1][0], q0B, it == tB, kc);

      bf16x8_t pA0, pA1;
      if (aAct) {
        pA0 = *(const bf16x8_t*)(&Ps[wave][0][0] + l16 * 72 + quad * 8);
        pA1 = *(const bf16x8_t*)(&Ps[wave][0][0] + l16 * 72 + 32 + quad * 8);
      }
      bf16x8_t pB0 = *(const bf16x8_t*)(&Ps[wave][1][0] + l16 * 72 + quad * 8);
      bf16x8_t pB1 = *(const bf16x8_t*)(&Ps[wave][1][0] + l16 * 72 + 32 + quad * 8);
      __builtin_amdgcn_s_setprio(1);
#pragma unroll
      for (int nt = 0; nt < 4; nt++) {
        bf16x8_t vf0 = *(const bf16x8_t*)(Vt + (nt * 16 + l16) * 72 + quad * 8);
        bf16x8_t vf1 = *(const bf16x8_t*)(Vt + (nt * 16 + l16) * 72 + 32 + quad * 8);
        if (aAct) {
          oA[nt] = __builtin_amdgcn_mfma_f32_16x16x32_bf16(pA0, vf0, oA[nt], 0, 0, 0);
          oA[nt] = __builtin_amdgcn_mfma_f32_16x16x32_bf16(pA1, vf1, oA[nt], 0, 0, 0);
        }
        oB[nt] = __builtin_amdgcn_mfma_f32_16x16x32_bf16(pB0, vf0, oB[nt], 0, 0, 0);
        oB[nt] = __builtin_amdgcn_mfma_f32_16x16x32_bf16(pB1, vf1, oB[nt], 0, 0, 0);
      }
      __builtin_amdgcn_s_setprio(0);

      __syncthreads();
      if (more) {
        *(bf16x8_t*)(Ks + kr0 * 72 + kc0) = nk0;
        *(bf16x8_t*)(Ks + (kr0 + 32) * 72 + kc0) = nk1;
#pragma unroll
        for (int i = 0; i < 8; i++) {
          bf16x2_t p2 = {nva[i], nvb[i]};
          *(bf16x2_t*)(Vt + (vs * 8 + i) * 72 + 2 * vp2) = p2;
        }
        __syncthreads();
      }
    }

#pragma unroll
    for (int nt = 0; nt < 4; nt++)
#pragma unroll
      for (int r = 0; r < 4; r++) {
        const int rqA = q0A + wave * 16 + quad * 4 + r;
        const int rqB = q0B + wave * 16 + quad * 4 + r;
        size_t aa = ((size_t)bsel * Ss + rqA) * Dd + (size_t)hsel * DHh + nt * 16 + l16;
        size_t ab = ((size_t)bsel * Ss + rqB) * Dd + (size_t)hsel * DHh + nt * 16 + l16;
        ctx[aa] = (bf16)(oA[nt][r] / lA[r]);
        ctx[ab] = (bf16)(oB[nt][r] / lB[r]);
      }
  }
}

// ---------------------------------------------------------------------------
extern "C" void kernel_launch(void* const* d_in, const int* in_sizes, int n_in,
                              void* d_out, int out_size, void* d_ws, size_t ws_size,
                              hipStream_t stream) {
  (void)in_sizes; (void)n_in; (void)out_size; (void)ws_size;
  const float* x = (const float*)d_in[0];
  const float* Wq = (const float*)d_in[1];
  const float* Wk = (const float*)d_in[2];
  const float* Wv = (const float*)d_in[3];
  const float* Wo = (const float*)d_in[4];
  const float* bo = (const float*)d_in[5];
  const float* W1 = (const float*)d_in[6];
  const float* b1 = (const float*)d_in[7];
  const float* W2 = (const float*)d_in[8];
  const float* b2 = (const float*)d_in[9];
  const float* ln1s = (const float*)d_in[10];
  const float* ln1b = (const float*)d_in[11];
  const float* ln2s = (const float*)d_in[12];
  const float* ln2b = (const float*)d_in[13];

  char* wsb = (char*)d_ws;
  const size_t MB = 1024 * 1024;
  bf16* Wqb = (bf16*)(wsb);
  bf16* Wkb = (bf16*)(wsb + 2 * MB);
  bf16* Wvb = (bf16*)(wsb + 4 * MB);
  bf16* Wob = (bf16*)(wsb + 6 * MB);
  bf16* W1b = (bf16*)(wsb + 8 * MB);
  bf16* W2b = (bf16*)(wsb + 16 * MB);
  bf16* h   = (bf16*)(wsb + 24 * MB);
  bf16* qkv = (bf16*)(wsb + 40 * MB);  // 48MB: 8192 x 3072 row-major [Q|K|V]
  bf16* ctx = (bf16*)(wsb + 88 * MB);
  bf16* x1  = (bf16*)(wsb + 104 * MB);
  bf16* h2  = ctx;
  bf16* ff1 = h;

  dim3 blk(256, 1, 1);
  dim3 blk8(512, 1, 1);

  CastArgs ca;
  ca.src[0] = Wq; ca.src[1] = Wk; ca.src[2] = Wv; ca.src[3] = Wo;
  ca.src[4] = W1; ca.src[5] = W2;
  ca.dst[0] = Wqb; ca.dst[1] = Wkb; ca.dst[2] = Wvb; ca.dst[3] = Wob;
  ca.dst[4] = W1b; ca.dst[5] = W2b;
  ca.n[0] = ca.n[1] = ca.n[2] = ca.n[3] = Dd * Dd;
  ca.n[4] = ca.n[5] = Dd * DFFc;
  cast_w_kernel<<<dim3((Dd * DFFc) / (256 * 4), 6, 1), blk, 0, stream>>>(ca);

  ln_kernel<float><<<dim3(NTOK, 1, 1), blk, 0, stream>>>(x, ln1s, ln1b, h);
  // QKV: M=8192, N=3072, K=1024. BN=128 -> grid (24, 32) = 768 blocks =
  // exactly 3 full CU-rounds (BN=256's 384 blocks was 1.5 rounds, 75% util).
  gemmk<128, 0><<<dim3(24, NTOK / 256, 1), blk8, 0, stream>>>(h, Wqb, nullptr, nullptr,
                                                              qkv, NTOK, NQKV, Dd);
  // dual-chain attn: grid (8, 64) = 512 blocks, balanced 34 slots each.
  attn_kernel<<<dim3(8, Bb * Hh, 1), blk, 0, stream>>>(qkv, ctx);
  // Wo: N=1024 -> BN=128, grid (8, 32) = 256 blocks (1 full round).
  gemmk<128, 1><<<dim3(8, NTOK / 256, 1), blk8, 0, stream>>>(ctx, Wob, bo, x, x1,
                                                             NTOK, Dd, Dd);
  ln_kernel<bf16><<<dim3(NTOK, 1, 1), blk, 0, stream>>>(x1, ln2s, ln2b, h2);
  // FF1: N=4096 -> BN=256, grid (16, 32) = 512 blocks (2 full rounds).
  gemmk<256, 2><<<dim3(16, NTOK / 256, 1), blk8, 0, stream>>>(h2, W1b, b1, nullptr, ff1,
                                                              NTOK, DFFc, Dd);
  // FF2: N=1024, K=4096 -> BN=128, grid (8, 32) = 256 blocks.
  gemmk<128, 3><<<dim3(8, NTOK / 256, 1), blk8, 0, stream>>>(ff1, W2b, b2, x1,
                                                             (float*)d_out, NTOK, Dd, DFFc);
}